// Round 2
// baseline (419.912 us; speedup 1.0000x reference)
//
#include <hip/hip_runtime.h>

// Problem constants (fixed by the reference): E=8, M=32768, K=1024, N=1024
#define M_DIM 32768
#define K_DIM 1024
#define N_DIM 1024
#define E_NUM 8

#define BM 128
#define BN 128
#define BK 64

typedef __attribute__((ext_vector_type(4))) int v4i;

// ---------------------------------------------------------------------------
// Pass 1a: pack x (int32 valued int8) -> int8, straight layout [M][K]
// Each thread: one int4 load (16B), one int store (4B packed bytes).
// ---------------------------------------------------------------------------
__global__ __launch_bounds__(256) void pack_x_kernel(const int4* __restrict__ x,
                                                     int* __restrict__ xq) {
    int i = blockIdx.x * 256 + threadIdx.x;
    int4 v = x[i];
    xq[i] = (v.x & 255) | ((v.y & 255) << 8) | ((v.z & 255) << 16) | (v.w << 24);
}

// ---------------------------------------------------------------------------
// Pass 1b: pack + transpose weight: [E][K][N] int32 -> [E][N][K] int8.
// Classic LDS-tiled transpose, 32x32 tiles, block (32,8).
// ---------------------------------------------------------------------------
__global__ __launch_bounds__(256) void pack_wt_kernel(const int* __restrict__ w,
                                                      signed char* __restrict__ wt) {
    __shared__ signed char tile[32][33];
    const int e  = blockIdx.z;
    const int k0 = blockIdx.y * 32;
    const int n0 = blockIdx.x * 32;
    const int tx = threadIdx.x;   // 0..31
    const int ty = threadIdx.y;   // 0..7
    const int* wp = w + ((size_t)e << 20);
#pragma unroll
    for (int i = 0; i < 32; i += 8) {
        tile[ty + i][tx] = (signed char)wp[(size_t)(k0 + ty + i) * N_DIM + n0 + tx];
    }
    __syncthreads();
    signed char* wo = wt + ((size_t)e << 20);
#pragma unroll
    for (int i = 0; i < 32; i += 8) {
        wo[(size_t)(n0 + ty + i) * K_DIM + k0 + tx] = tile[tx][ty + i];
    }
}

// ---------------------------------------------------------------------------
// Pass 2: grouped int8 GEMM + fused dequant.
//   out[m][n] = (sum_k x[m][k]*w[e(m)][k][n]) * scale[e(m)][n] * pts[m]
// m97-style structure: 128x128 tile, 256 threads (4 waves), each wave 64x64
// via 4x4 of mfma_i32_16x16x64_i8. A = xq[M][K], B^T = wtq[E][N][K].
// Boundary tiles (expert change inside the 128 rows) loop over the experts
// present and write only that expert's row segment.
//
// group_list dtype sniffing: the reference casts to int64, but under default
// JAX config (x64 disabled) the device buffer is int32. Little-endian int64
// values < 2^31 viewed as int32 give [v0,0,v1,0,...] -> g32[7]==0; a true
// int32 buffer has g32[7] == M (last cumulative offset == M). Branch on that.
// ---------------------------------------------------------------------------
__global__ __launch_bounds__(256) void gmm_kernel(
    const signed char* __restrict__ xq,    // [M][K] int8
    const signed char* __restrict__ wtq,   // [E][N][K] int8
    const float* __restrict__ scale,       // [E][N]
    const float* __restrict__ pts,         // [M]
    const int* __restrict__ g32,           // group_list viewed as int32
    float* __restrict__ out)               // [M][N] fp32
{
    __shared__ signed char As[BM * BK];    // 8 KB
    __shared__ signed char Bs[BN * BK];    // 8 KB

    const int tid  = threadIdx.x;
    const int lane = tid & 63;
    const int wv   = tid >> 6;             // wave 0..3
    const int m0   = blockIdx.x * BM;
    const int n0   = blockIdx.y * BN;

    // expert range covered by this M-tile (dtype-robust group_list read)
    const bool g_is_i64 = (g32[7] != M_DIM);
    int cum[E_NUM];
#pragma unroll
    for (int e = 0; e < E_NUM; ++e)
        cum[e] = g_is_i64 ? g32[2 * e] : g32[e];   // low half suffices (< 2^31)

    int e0 = 0;
    while (e0 < E_NUM - 1 && cum[e0] <= m0) ++e0;
    int e1 = 0;
    while (e1 < E_NUM - 1 && cum[e1] <= m0 + BM - 1) ++e1;

    const int wm    = (wv >> 1) * 64;      // wave row offset in tile
    const int wn    = (wv & 1) * 64;       // wave col offset in tile
    const int row_a = lane & 15;
    const int quad  = lane >> 4;

    // staging geometry (shared by A and B): chunk = 1024B = 16 rows of 64B
    const int st_row = (lane >> 2);        // 0..15 within chunk
    const int st_col = (lane & 3) * 16;    // 0/16/32/48

    const signed char* xg = xq + (size_t)m0 * K_DIM;

    for (int e = e0; e <= e1; ++e) {
        const int lo = (e == 0) ? 0 : cum[e - 1];
        const int hi = cum[e];
        if (hi <= lo) continue;            // empty expert (block-uniform branch)
        int slo = lo > m0 ? lo : m0;
        int shi = hi < m0 + BM ? hi : m0 + BM;
        if (slo >= shi) continue;

        const signed char* wg = wtq + ((size_t)e << 20) + (size_t)n0 * K_DIM;

        v4i acc[4][4];
#pragma unroll
        for (int i = 0; i < 4; ++i)
#pragma unroll
            for (int j = 0; j < 4; ++j)
                acc[i][j] = (v4i){0, 0, 0, 0};

        for (int k0 = 0; k0 < K_DIM; k0 += BK) {
            // global -> LDS staging, 16B per lane, wave-uniform LDS base
#pragma unroll
            for (int s = 0; s < 2; ++s) {
                const int chunk = s * 4 + wv;              // 0..7
                const int row   = chunk * 16 + st_row;     // 0..127
                __builtin_amdgcn_global_load_lds(
                    (const __attribute__((address_space(1))) void*)
                        (xg + (size_t)row * K_DIM + k0 + st_col),
                    (__attribute__((address_space(3))) void*)(As + chunk * 1024),
                    16, 0, 0);
                __builtin_amdgcn_global_load_lds(
                    (const __attribute__((address_space(1))) void*)
                        (wg + (size_t)row * K_DIM + k0 + st_col),
                    (__attribute__((address_space(3))) void*)(Bs + chunk * 1024),
                    16, 0, 0);
            }
            __syncthreads();

            v4i af[4], bf[4];
#pragma unroll
            for (int i = 0; i < 4; ++i)
                af[i] = *(const v4i*)(As + (wm + i * 16 + row_a) * BK + quad * 16);
#pragma unroll
            for (int j = 0; j < 4; ++j)
                bf[j] = *(const v4i*)(Bs + (wn + j * 16 + row_a) * BK + quad * 16);

#pragma unroll
            for (int i = 0; i < 4; ++i)
#pragma unroll
                for (int j = 0; j < 4; ++j)
                    acc[i][j] = __builtin_amdgcn_mfma_i32_16x16x64_i8(
                        af[i], bf[j], acc[i][j], 0, 0, 0);

            __syncthreads();
        }

        // epilogue: dequant + segment-masked write
#pragma unroll
        for (int i = 0; i < 4; ++i) {
            const int rb = m0 + wm + i * 16 + quad * 4;
#pragma unroll
            for (int j = 0; j < 4; ++j) {
                const int c = n0 + wn + j * 16 + row_a;
                const float sc = scale[e * N_DIM + c];
#pragma unroll
                for (int r = 0; r < 4; ++r) {
                    const int rr = rb + r;
                    if (rr >= slo && rr < shi)
                        out[(size_t)rr * N_DIM + c] =
                            (float)acc[i][j][r] * sc * pts[rr];
                }
            }
        }
    }
}

// ---------------------------------------------------------------------------
extern "C" void kernel_launch(void* const* d_in, const int* in_sizes, int n_in,
                              void* d_out, int out_size, void* d_ws, size_t ws_size,
                              hipStream_t stream) {
    const int*   x     = (const int*)d_in[0];
    const int*   w     = (const int*)d_in[1];
    const float* scale = (const float*)d_in[2];
    const float* pts   = (const float*)d_in[3];
    const int*   g32   = (const int*)d_in[4];   // int32 or int64 — sniffed in-kernel
    float*       out   = (float*)d_out;

    signed char* xq  = (signed char*)d_ws;                    // 32 MB
    signed char* wtq = xq + (size_t)M_DIM * K_DIM;            // 8 MB

    // Pass 1a: pack x
    pack_x_kernel<<<(M_DIM * K_DIM / 4) / 256, 256, 0, stream>>>(
        (const int4*)x, (int*)xq);

    // Pass 1b: pack + transpose weight
    pack_wt_kernel<<<dim3(N_DIM / 32, K_DIM / 32, E_NUM), dim3(32, 8), 0, stream>>>(
        w, wtq);

    // Pass 2: grouped GEMM + dequant
    gmm_kernel<<<dim3(M_DIM / BM, N_DIM / BN), 256, 0, stream>>>(
        xq, wtq, scale, pts, g32, out);
}

// Round 3
// 334.874 us; speedup vs baseline: 1.2539x; 1.2539x over previous
//
#include <hip/hip_runtime.h>

// Problem constants (fixed by the reference): E=8, M=32768, K=1024, N=1024
#define M_DIM 32768
#define K_DIM 1024
#define N_DIM 1024
#define E_NUM 8

#define BM 128
#define BN 128
#define BK 128            // k-bytes staged per step (full 128B cache lines)
#define KSTEPS (K_DIM / BK)   // 8

typedef __attribute__((ext_vector_type(4))) int v4i;

// ---------------------------------------------------------------------------
// Pass 1a: pack x (int32 valued int8) -> int8 [M][K]. 64B in / 16B out per
// thread: 4x int4 loads, 1x int4 store. Grid = M*K/16/256 = 8192 blocks.
// ---------------------------------------------------------------------------
__global__ __launch_bounds__(256) void pack_x_kernel(const int4* __restrict__ x,
                                                     int4* __restrict__ xq) {
    const int i = blockIdx.x * 256 + threadIdx.x;
    int4 a = x[i * 4 + 0], b = x[i * 4 + 1], c = x[i * 4 + 2], d = x[i * 4 + 3];
    int4 o;
    o.x = (a.x & 255) | ((a.y & 255) << 8) | ((a.z & 255) << 16) | (a.w << 24);
    o.y = (b.x & 255) | ((b.y & 255) << 8) | ((b.z & 255) << 16) | (b.w << 24);
    o.z = (c.x & 255) | ((c.y & 255) << 8) | ((c.z & 255) << 16) | (c.w << 24);
    o.w = (d.x & 255) | ((d.y & 255) << 8) | ((d.z & 255) << 16) | (d.w << 24);
    xq[i] = o;
}

// ---------------------------------------------------------------------------
// Pass 1b: pack + transpose weight [E][K][N] int32 -> [E][N][K] int8.
// Tile: 64 n x 256 k per block (256 threads). Loads: 256B contiguous per
// wave per k-row. Stores: one full 256B row (64 ints) per wave -> coalesced.
// Grid: (N/64, K/256, E) = (16, 4, 8).
// ---------------------------------------------------------------------------
__global__ __launch_bounds__(256) void pack_wt_kernel(const int* __restrict__ w,
                                                      int* __restrict__ wt) {
    __shared__ signed char tile[64][260];   // [n][k], +4 pad keeps banks spread
    const int e    = blockIdx.z;
    const int n0   = blockIdx.x * 64;
    const int k0   = blockIdx.y * 256;
    const int tid  = threadIdx.x;
    const int lane = tid & 63;
    const int wv   = tid >> 6;

    const int* wp = w + ((size_t)e << 20);
#pragma unroll 4
    for (int i = 0; i < 64; ++i) {
        const int k = wv * 64 + i;          // each wave: 64 k-rows
        tile[lane][k] = (signed char)wp[(size_t)(k0 + k) * N_DIM + n0 + lane];
    }
    __syncthreads();

    int* wo = wt + ((size_t)e << 18);       // int units: 1MB/4 per expert
#pragma unroll
    for (int i = 0; i < 16; ++i) {
        const int n = i * 4 + wv;
        const int v = *(const int*)&tile[n][lane * 4];   // 260 % 4 == 0, aligned
        wo[(size_t)(n0 + n) * (K_DIM / 4) + (k0 >> 2) + lane] = v;
    }
}

// ---------------------------------------------------------------------------
// Pass 2: grouped int8 GEMM + fused dequant.
// m97-lineage, upgraded: BK=128 (full-line staging rows), double-buffered LDS
// (2 x 32KB), issue-early prefetch (stage t+1 right after the barrier, compute
// t, then barrier -> the vmcnt(0) drain overlaps a full compute phase), and
// XOR-swizzled k-slots (slot ^ (row&7)) applied at FETCH time so frag ds_reads
// are bank-balanced while global_load_lds stays contiguous (HW constraint:
// LDS dst = wave base + lane*16).
// XCD swizzle: nt = gid&7 -> each XCD keeps its 1MB B-slice L2-resident.
// group_list dtype sniffed (int32 vs int64) via g32[7] == M.
// ---------------------------------------------------------------------------
__global__ __launch_bounds__(256, 2) void gmm_kernel(
    const signed char* __restrict__ xq,    // [M][K] int8
    const signed char* __restrict__ wtq,   // [E][N][K] int8
    const float* __restrict__ scale,       // [E][N]
    const float* __restrict__ pts,         // [M]
    const int* __restrict__ g32,           // group_list viewed as int32
    float* __restrict__ out)               // [M][N] fp32
{
    __shared__ signed char As[2][BM * BK]; // 2 x 16KB
    __shared__ signed char Bs[2][BN * BK]; // 2 x 16KB

    const int tid  = threadIdx.x;
    const int lane = tid & 63;
    const int wv   = tid >> 6;             // wave 0..3
    const int gid  = blockIdx.x;
    const int m0   = (gid >> 3) * BM;      // consecutive gids span n-tiles ->
    const int n0   = (gid & 7) * BN;       // XCD round-robin pins n per XCD

    // group_list (dtype-robust)
    const bool g_is_i64 = (g32[7] != M_DIM);
    int cum[E_NUM];
#pragma unroll
    for (int e = 0; e < E_NUM; ++e)
        cum[e] = g_is_i64 ? g32[2 * e] : g32[e];
    int e0 = 0;
    while (e0 < E_NUM - 1 && cum[e0] <= m0) ++e0;
    int e1 = 0;
    while (e1 < E_NUM - 1 && cum[e1] <= m0 + BM - 1) ++e1;

    const int wm    = (wv >> 1) * 64;
    const int wn    = (wv & 1) * 64;
    const int row_a = lane & 15;
    const int quad  = lane >> 4;
    const int rx    = row_a & 7;           // row&7 for all frag rows

    // staging lane geometry: chunk = 8 rows x 128B = 1KB
    const int st_r = lane >> 3;                     // row in chunk 0..7
    const int st_c = ((lane & 7) ^ st_r) * 16;      // swizzled col bytes

    const signed char* xg = xq + (size_t)m0 * K_DIM;

    for (int e = e0; e <= e1; ++e) {
        const int lo = (e == 0) ? 0 : cum[e - 1];
        const int hi = cum[e];
        if (hi <= lo) continue;            // block-uniform
        const int slo = lo > m0 ? lo : m0;
        const int shi = hi < m0 + BM ? hi : m0 + BM;
        if (slo >= shi) continue;

        const signed char* wg = wtq + ((size_t)e << 20) + (size_t)n0 * K_DIM;

        // prefetch epilogue scalars (fly during the whole GEMM)
        float sc[4], pt[16];
#pragma unroll
        for (int j = 0; j < 4; ++j)
            sc[j] = scale[e * N_DIM + n0 + wn + j * 16 + row_a];
#pragma unroll
        for (int i = 0; i < 4; ++i)
#pragma unroll
            for (int r = 0; r < 4; ++r)
                pt[i * 4 + r] = pts[m0 + wm + i * 16 + quad * 4 + r];

        v4i acc[4][4];
#pragma unroll
        for (int i = 0; i < 4; ++i)
#pragma unroll
            for (int j = 0; j < 4; ++j)
                acc[i][j] = (v4i){0, 0, 0, 0};

        auto stage = [&](int t, int b) {
            const int kb = t * BK;
#pragma unroll
            for (int s = 0; s < 4; ++s) {
                const int c   = s * 4 + wv;        // chunk 0..15
                const int row = c * 8 + st_r;      // 0..127
                __builtin_amdgcn_global_load_lds(
                    (const __attribute__((address_space(1))) void*)
                        (xg + (size_t)row * K_DIM + kb + st_c),
                    (__attribute__((address_space(3))) void*)(&As[b][c * 1024]),
                    16, 0, 0);
                __builtin_amdgcn_global_load_lds(
                    (const __attribute__((address_space(1))) void*)
                        (wg + (size_t)row * K_DIM + kb + st_c),
                    (__attribute__((address_space(3))) void*)(&Bs[b][c * 1024]),
                    16, 0, 0);
            }
        };

        stage(0, 0);
        __syncthreads();

        for (int t = 0; t < KSTEPS; ++t) {
            const int cur = t & 1;
            if (t + 1 < KSTEPS) stage(t + 1, cur ^ 1);   // issue, don't wait

#pragma unroll
            for (int w = 0; w < 2; ++w) {                // two K=64 windows
                const int sa = ((w << 2) + quad) ^ rx;   // swizzled 16B slot
                v4i af[4], bf[4];
#pragma unroll
                for (int i = 0; i < 4; ++i)
                    af[i] = *(const v4i*)(&As[cur][(wm + i * 16 + row_a) * BK + sa * 16]);
#pragma unroll
                for (int j = 0; j < 4; ++j)
                    bf[j] = *(const v4i*)(&Bs[cur][(wn + j * 16 + row_a) * BK + sa * 16]);
#pragma unroll
                for (int i = 0; i < 4; ++i)
#pragma unroll
                    for (int j = 0; j < 4; ++j)
                        acc[i][j] = __builtin_amdgcn_mfma_i32_16x16x64_i8(
                            af[i], bf[j], acc[i][j], 0, 0, 0);
            }
            __syncthreads();    // drains the t+1 prefetch -- after compute
        }

        // epilogue: dequant + segment-masked write
#pragma unroll
        for (int i = 0; i < 4; ++i) {
            const int rb = m0 + wm + i * 16 + quad * 4;
#pragma unroll
            for (int j = 0; j < 4; ++j) {
                const int c = n0 + wn + j * 16 + row_a;
#pragma unroll
                for (int r = 0; r < 4; ++r) {
                    const int rr = rb + r;
                    if (rr >= slo && rr < shi)
                        out[(size_t)rr * N_DIM + c] =
                            (float)acc[i][j][r] * sc[j] * pt[i * 4 + r];
                }
            }
        }
    }
}

// ---------------------------------------------------------------------------
extern "C" void kernel_launch(void* const* d_in, const int* in_sizes, int n_in,
                              void* d_out, int out_size, void* d_ws, size_t ws_size,
                              hipStream_t stream) {
    const int*   x     = (const int*)d_in[0];
    const int*   w     = (const int*)d_in[1];
    const float* scale = (const float*)d_in[2];
    const float* pts   = (const float*)d_in[3];
    const int*   g32   = (const int*)d_in[4];   // int32 or int64 -- sniffed in-kernel
    float*       out   = (float*)d_out;

    signed char* xq  = (signed char*)d_ws;                 // 32 MB
    signed char* wtq = xq + (size_t)M_DIM * K_DIM;         // 8 MB

    pack_x_kernel<<<M_DIM * K_DIM / 16 / 256, 256, 0, stream>>>(
        (const int4*)x, (int4*)xq);

    pack_wt_kernel<<<dim3(N_DIM / 64, K_DIM / 256, E_NUM), 256, 0, stream>>>(
        w, (int*)wtq);

    gmm_kernel<<<(M_DIM / BM) * (N_DIM / BN), 256, 0, stream>>>(
        xq, wtq, scale, pts, g32, out);
}